// Round 1
// baseline (1556.075 us; speedup 1.0000x reference)
//
#include <hip/hip_runtime.h>
#include <math.h>

typedef _Float16 h2f __attribute__((ext_vector_type(2)));

__device__ __forceinline__ float fdot2f(h2f a, h2f b, float c) {
#if __has_builtin(__builtin_amdgcn_fdot2)
  return __builtin_amdgcn_fdot2(a, b, c, false);
#else
  return c + (float)a[0] * (float)b[0] + (float)a[1] * (float)b[1];
#endif
}

__device__ __forceinline__ int clampi(int v, int lo, int hi) {
  return v < lo ? lo : (v > hi ? hi : v);
}

// ---------------------------------------------------------------------------
// Kernel A: per-token: ft gather + char conv (3,4,5) -> lstm_in[1024][450]
// ---------------------------------------------------------------------------
__global__ __launch_bounds__(64) void k_token(
    const float* __restrict__ fast_text, const float* __restrict__ char_table,
    const float* __restrict__ w3, const float* __restrict__ b3,
    const float* __restrict__ w4, const float* __restrict__ b4,
    const float* __restrict__ w5, const float* __restrict__ b5,
    const int* __restrict__ word_ids, const int* __restrict__ char_ids,
    float* __restrict__ lstm_in) {
  const int t = blockIdx.x;
  const int tid = threadIdx.x;
  __shared__ float ce[16][16];  // ce[l][ci]
  for (int i = tid; i < 256; i += 64) {
    int l = i >> 4, ci = i & 15;
    ce[l][ci] = char_table[char_ids[t * 16 + l] * 16 + ci];
  }
  __syncthreads();
  const int wid = word_ids[t];
  for (int d = tid; d < 300; d += 64)
    lstm_in[t * 450 + d] = fast_text[wid * 300 + d];
  const int f = tid;
  if (f < 50) {
    // k = 3, 14 positions
    {
      float acc[14];
#pragma unroll
      for (int p = 0; p < 14; ++p) acc[p] = 0.f;
      for (int ci = 0; ci < 16; ++ci) {
#pragma unroll
        for (int kk = 0; kk < 3; ++kk) {
          float wv = w3[(f * 16 + ci) * 3 + kk];
#pragma unroll
          for (int p = 0; p < 14; ++p) acc[p] += ce[p + kk][ci] * wv;
        }
      }
      float m = acc[0];
#pragma unroll
      for (int p = 1; p < 14; ++p) m = fmaxf(m, acc[p]);
      lstm_in[t * 450 + 300 + f] = fmaxf(0.f, m + b3[f]);
    }
    // k = 4, 13 positions
    {
      float acc[13];
#pragma unroll
      for (int p = 0; p < 13; ++p) acc[p] = 0.f;
      for (int ci = 0; ci < 16; ++ci) {
#pragma unroll
        for (int kk = 0; kk < 4; ++kk) {
          float wv = w4[(f * 16 + ci) * 4 + kk];
#pragma unroll
          for (int p = 0; p < 13; ++p) acc[p] += ce[p + kk][ci] * wv;
        }
      }
      float m = acc[0];
#pragma unroll
      for (int p = 1; p < 13; ++p) m = fmaxf(m, acc[p]);
      lstm_in[t * 450 + 350 + f] = fmaxf(0.f, m + b4[f]);
    }
    // k = 5, 12 positions
    {
      float acc[12];
#pragma unroll
      for (int p = 0; p < 12; ++p) acc[p] = 0.f;
      for (int ci = 0; ci < 16; ++ci) {
#pragma unroll
        for (int kk = 0; kk < 5; ++kk) {
          float wv = w5[(f * 16 + ci) * 5 + kk];
#pragma unroll
          for (int p = 0; p < 12; ++p) acc[p] += ce[p + kk][ci] * wv;
        }
      }
      float m = acc[0];
#pragma unroll
      for (int p = 1; p < 12; ++p) m = fmaxf(m, acc[p]);
      lstm_in[t * 450 + 400 + f] = fmaxf(0.f, m + b5[f]);
    }
  }
}

// ---------------------------------------------------------------------------
// Generic fp32 GEMM: C[M][N] = A[M][K] @ W[N][K]^T (+ bias[N] if non-null)
// 64x64 tile, 256 threads, 4x4 micro-tile.
// ---------------------------------------------------------------------------
__global__ __launch_bounds__(256) void gemm_nt(
    const float* __restrict__ A, const float* __restrict__ W,
    const float* __restrict__ bias, float* __restrict__ C,
    int M, int N, int K) {
  __shared__ float As[16][64];
  __shared__ float Ws[16][64];
  const int tid = threadIdx.x;
  const int tx = tid & 15, ty = tid >> 4;
  const int r0 = blockIdx.x * 64, c0 = blockIdx.y * 64;
  float acc[4][4] = {};
  for (int k0 = 0; k0 < K; k0 += 16) {
    for (int i = tid; i < 1024; i += 256) {
      int rr = i >> 4, kk = i & 15;
      int r = r0 + rr, k = k0 + kk;
      As[kk][rr] = (r < M && k < K) ? A[r * K + k] : 0.f;
      int c = c0 + rr;
      Ws[kk][rr] = (c < N && k < K) ? W[c * K + k] : 0.f;
    }
    __syncthreads();
#pragma unroll
    for (int kk = 0; kk < 16; ++kk) {
      const float4 av = *(const float4*)(&As[kk][ty * 4]);
      const float4 wv = *(const float4*)(&Ws[kk][tx * 4]);
      float a[4] = {av.x, av.y, av.z, av.w};
      float w[4] = {wv.x, wv.y, wv.z, wv.w};
#pragma unroll
      for (int i = 0; i < 4; ++i)
#pragma unroll
        for (int j = 0; j < 4; ++j) acc[i][j] += a[i] * w[j];
    }
    __syncthreads();
  }
#pragma unroll
  for (int i = 0; i < 4; ++i) {
    int r = r0 + ty * 4 + i;
    if (r >= M) continue;
#pragma unroll
    for (int j = 0; j < 4; ++j) {
      int c = c0 + tx * 4 + j;
      if (c < N) C[r * N + c] = acc[i][j] + (bias ? bias[c] : 0.f);
    }
  }
}

// ---------------------------------------------------------------------------
// Kernel C: LSTM recurrence, one block per direction.
// 640 threads: threads 0..599 each own one z-row (Wh row in 75 packed-f16
// VGPRs); threads 0..149 own gate/cell for hidden unit j.
// ---------------------------------------------------------------------------
__global__ __launch_bounds__(640) void k_lstm(
    const float* __restrict__ xprojF, const float* __restrict__ xprojB,
    const float* __restrict__ Wh_f, const float* __restrict__ Wh_b,
    float* __restrict__ keys) {
  const int dir = blockIdx.x;
  const float* __restrict__ xp = dir ? xprojB : xprojF;
  const float* __restrict__ Wh = dir ? Wh_b : Wh_f;
  const int j = threadIdx.x;

  __shared__ float zsh[600];
  __shared__ h2f hsh[76];  // h packed as f16 pairs (150 used + 2 zero pad)

  h2f whh[75];
  if (j < 600) {
    const float2* Wh2 = (const float2*)Wh;  // row stride 150 floats = 75 float2
#pragma unroll
    for (int kk = 0; kk < 75; ++kk) {
      float2 w = Wh2[j * 75 + kk];
      h2f v;
      v[0] = (_Float16)w.x;
      v[1] = (_Float16)w.y;
      whh[kk] = v;
    }
  }
  if (j < 76) {
    h2f z;
    z[0] = (_Float16)0.f;
    z[1] = (_Float16)0.f;
    hsh[j] = z;
  }
  float c = 0.f;
  __syncthreads();

  for (int step = 0; step < 1024; ++step) {
    const int t = dir ? (1023 - step) : step;
    if (j < 600) {
      float acc = xp[t * 600 + j];
#pragma unroll
      for (int kk = 0; kk < 75; ++kk) acc = fdot2f(whh[kk], hsh[kk], acc);
      zsh[j] = acc;
    }
    __syncthreads();
    if (j < 150) {
      float zi = zsh[j], zf = zsh[150 + j], zg = zsh[300 + j], zo = zsh[450 + j];
      float ig = 1.f / (1.f + expf(-zi));
      float fg = 1.f / (1.f + expf(-zf));
      float gg = tanhf(zg);
      float og = 1.f / (1.f + expf(-zo));
      c = fg * c + ig * gg;
      float h = og * tanhf(c);
      keys[t * 300 + dir * 150 + j] = h;
      ((_Float16*)hsh)[j] = (_Float16)h;
    }
    __syncthreads();
  }
}

// ---------------------------------------------------------------------------
// Kernel D: span scorer -> enc[512][1000]
// ---------------------------------------------------------------------------
__global__ __launch_bounds__(320) void k_span(
    const float* __restrict__ keys, const float* __restrict__ lstm_in,
    const float* __restrict__ W1, const float* __restrict__ b1,
    const float* __restrict__ W2, const float* __restrict__ b2,
    const float* __restrict__ w_out, const float* __restrict__ feat_table,
    const int* __restrict__ espans, float* __restrict__ enc) {
  const int e = blockIdx.x;
  const int tid = threadIdx.x;
  const int s = espans[e * 4 + 0];
  const int en = espans[e * 4 + 1];
  const int f0 = espans[e * 4 + 2];
  const int f1 = espans[e * 4 + 3];

  __shared__ float ksh[10][300];
  __shared__ float hsh[10][152];
  __shared__ float h2sh[10][152];
  __shared__ float att[10];
  __shared__ float scl[2];

  for (int i = tid; i < 3000; i += 320) {
    int p = i / 300, d = i % 300;
    int row = clampi(s + p, 0, 1023);
    ksh[p][d] = keys[row * 300 + d];
  }
  __syncthreads();

  // hsc1 = relu(k_sp @ W1 + b1): thread jj computes column jj for all p
  if (tid < 152) {
    int jj = tid;
    if (jj < 150) {
      float acc[10];
#pragma unroll
      for (int p = 0; p < 10; ++p) acc[p] = b1[jj];
      for (int k = 0; k < 300; k += 4) {
        float w0 = W1[(k + 0) * 150 + jj];
        float w1 = W1[(k + 1) * 150 + jj];
        float w2 = W1[(k + 2) * 150 + jj];
        float w3 = W1[(k + 3) * 150 + jj];
#pragma unroll
        for (int p = 0; p < 10; ++p) {
          const float4 kv = *(const float4*)(&ksh[p][k]);
          acc[p] += kv.x * w0 + kv.y * w1 + kv.z * w2 + kv.w * w3;
        }
      }
#pragma unroll
      for (int p = 0; p < 10; ++p) hsh[p][jj] = fmaxf(acc[p], 0.f);
    } else {
#pragma unroll
      for (int p = 0; p < 10; ++p) hsh[p][jj] = 0.f;  // pad cols 150,151
    }
  }
  __syncthreads();

  // hsc2 = relu(hsc1 @ W2 + b2)
  if (tid < 150) {
    int jj = tid;
    float acc[10];
#pragma unroll
    for (int p = 0; p < 10; ++p) acc[p] = b2[jj];
    for (int k = 0; k < 152; k += 4) {
      float w0 = (k + 0 < 150) ? W2[(k + 0) * 150 + jj] : 0.f;
      float w1 = (k + 1 < 150) ? W2[(k + 1) * 150 + jj] : 0.f;
      float w2 = (k + 2 < 150) ? W2[(k + 2) * 150 + jj] : 0.f;
      float w3 = (k + 3 < 150) ? W2[(k + 3) * 150 + jj] : 0.f;
#pragma unroll
      for (int p = 0; p < 10; ++p) {
        const float4 hv = *(const float4*)(&hsh[p][k]);
        acc[p] += hv.x * w0 + hv.y * w1 + hv.z * w2 + hv.w * w3;
      }
    }
#pragma unroll
    for (int p = 0; p < 10; ++p) h2sh[p][jj] = fmaxf(acc[p], 0.f);
  }
  __syncthreads();

  // logits (masked) + feat norms in parallel
  if (tid < 10) {
    float lg = -1e30f;
    if (tid < en - s) {
      float d = 0.f;
      for (int k = 0; k < 150; ++k) d += h2sh[tid][k] * w_out[k];
      lg = d;
    }
    att[tid] = lg;
  }
  if (tid >= 64 && tid < 66) {
    int r = tid - 64;
    int fi = (r == 0) ? f0 : f1;
    float nsq = 0.f;
    for (int k = 0; k < 50; ++k) {
      float v = feat_table[fi * 50 + k];
      nsq += v * v;
    }
    float n = sqrtf(nsq);
    scl[r] = fminf(1.f, 1.f / fmaxf(n, 1e-7f));
  }
  __syncthreads();

  if (tid == 0) {
    float m = -1e30f;
    for (int p = 0; p < 10; ++p) m = fmaxf(m, att[p]);
    float ex[10];
    float ssum = 0.f;
    for (int p = 0; p < 10; ++p) {
      ex[p] = expf(att[p] - m);
      ssum += ex[p];
    }
    for (int p = 0; p < 10; ++p) att[p] = ex[p] / ssum;
  }
  __syncthreads();

  // enc = [xf, xl, xh, fs]
  if (tid < 300) {
    int d = tid;
    float xf = keys[s * 300 + d];
    float xl = keys[(en - 1) * 300 + d];
    float xh = 0.f;
#pragma unroll
    for (int p = 0; p < 10; ++p) {
      int row = clampi(s + p, 0, 1023);
      xh += att[p] * lstm_in[row * 450 + d];  // values = ft = lstm_in[:, :300]
    }
    enc[e * 1000 + d] = xf;
    enc[e * 1000 + 300 + d] = xl;
    enc[e * 1000 + 600 + d] = xh;
  }
  if (tid < 100) {
    int r = tid / 50, cc = tid % 50;
    int fi = (r == 0) ? f0 : f1;
    enc[e * 1000 + 900 + tid] = feat_table[fi * 50 + cc] * scl[r];
  }
}

// ---------------------------------------------------------------------------
// Kernel E: small = enc @ affine_W + affine_b   (4 spans per block)
// ---------------------------------------------------------------------------
__global__ __launch_bounds__(320) void k_affine(
    const float* __restrict__ enc, const float* __restrict__ W,
    const float* __restrict__ bias, float* __restrict__ small) {
  const int e0 = blockIdx.x * 4;
  const int tid = threadIdx.x;
  __shared__ float es[4][1000];
  for (int i = tid; i < 4000; i += 320) es[i / 1000][i % 1000] = enc[e0 * 1000 + i];
  __syncthreads();
  if (tid < 300) {
    float a0 = bias[tid], a1 = bias[tid], a2 = bias[tid], a3 = bias[tid];
    for (int k = 0; k < 1000; k += 4) {
      float w0 = W[(k + 0) * 300 + tid];
      float w1 = W[(k + 1) * 300 + tid];
      float w2 = W[(k + 2) * 300 + tid];
      float w3 = W[(k + 3) * 300 + tid];
      const float4 v0 = *(const float4*)(&es[0][k]);
      const float4 v1 = *(const float4*)(&es[1][k]);
      const float4 v2 = *(const float4*)(&es[2][k]);
      const float4 v3 = *(const float4*)(&es[3][k]);
      a0 += v0.x * w0 + v0.y * w1 + v0.z * w2 + v0.w * w3;
      a1 += v1.x * w0 + v1.y * w1 + v1.z * w2 + v1.w * w3;
      a2 += v2.x * w0 + v2.y * w1 + v2.z * w2 + v2.w * w3;
      a3 += v3.x * w0 + v3.y * w1 + v3.z * w2 + v3.w * w3;
    }
    small[(e0 + 0) * 300 + tid] = a0;
    small[(e0 + 1) * 300 + tid] = a1;
    small[(e0 + 2) * 300 + tid] = a2;
    small[(e0 + 3) * 300 + tid] = a3;
  }
}

// ---------------------------------------------------------------------------
// actors renorm
// ---------------------------------------------------------------------------
__global__ __launch_bounds__(64) void k_renorm(
    const float* __restrict__ actors, float* __restrict__ actorsN) {
  const int a = blockIdx.x;
  const int l = threadIdx.x;
  float nsq = 0.f;
  for (int d = l; d < 300; d += 64) {
    float v = actors[a * 300 + d];
    nsq += v * v;
  }
  for (int off = 32; off; off >>= 1) nsq += __shfl_down(nsq, off);
  nsq = __shfl(nsq, 0);
  float sc = fminf(1.f, 1.f / fmaxf(sqrtf(nsq), 1e-7f));
  for (int d = l; d < 300; d += 64) actorsN[a * 300 + d] = actors[a * 300 + d] * sc;
}

// ---------------------------------------------------------------------------
// logsumexp over rows of score_link (2000 x 512)
// ---------------------------------------------------------------------------
__global__ __launch_bounds__(64) void k_lse(
    const float* __restrict__ link, float* __restrict__ out) {
  const int a = blockIdx.x;
  const int l = threadIdx.x;
  float v[8];
  float m = -1e30f;
#pragma unroll
  for (int i = 0; i < 8; ++i) {
    v[i] = link[a * 512 + l + i * 64];
    m = fmaxf(m, v[i]);
  }
  for (int off = 32; off; off >>= 1) m = fmaxf(m, __shfl_xor(m, off));
  float ssum = 0.f;
#pragma unroll
  for (int i = 0; i < 8; ++i) ssum += expf(v[i] - m);
  for (int off = 32; off; off >>= 1) ssum += __shfl_xor(ssum, off);
  if (l == 0) out[a] = logf(ssum) + m;
}

// ---------------------------------------------------------------------------
extern "C" void kernel_launch(void* const* d_in, const int* in_sizes, int n_in,
                              void* d_out, int out_size, void* d_ws, size_t ws_size,
                              hipStream_t stream) {
  const float* fast_text = (const float*)d_in[0];
  const float* actor_matrix = (const float*)d_in[1];
  const float* char_table = (const float*)d_in[2];
  const float* w3 = (const float*)d_in[3];
  const float* b3 = (const float*)d_in[4];
  const float* w4 = (const float*)d_in[5];
  const float* b4 = (const float*)d_in[6];
  const float* w5 = (const float*)d_in[7];
  const float* b5 = (const float*)d_in[8];
  const float* Wi_f = (const float*)d_in[9];
  const float* Wh_f = (const float*)d_in[10];
  const float* b_f = (const float*)d_in[11];
  const float* Wi_b = (const float*)d_in[12];
  const float* Wh_b = (const float*)d_in[13];
  const float* b_b = (const float*)d_in[14];
  const float* alpha_W1 = (const float*)d_in[15];
  const float* alpha_b1 = (const float*)d_in[16];
  const float* alpha_W2 = (const float*)d_in[17];
  const float* alpha_b2 = (const float*)d_in[18];
  const float* alpha_w_out = (const float*)d_in[19];
  const float* feat_table = (const float*)d_in[20];
  const float* affine_W = (const float*)d_in[21];
  const float* affine_b = (const float*)d_in[22];
  const int* word_ids = (const int*)d_in[23];
  const int* char_ids = (const int*)d_in[24];
  const int* espans = (const int*)d_in[25];

  float* ws = (float*)d_ws;
  float* lstm_in = ws;                 // 1024*450 = 460800
  float* xpF = lstm_in + 460800;       // 1024*600 = 614400
  float* xpB = xpF + 614400;           // 614400
  float* keys = xpB + 614400;          // 1024*300 = 307200
  float* enc = keys + 307200;          // 512*1000 = 512000
  float* small = enc + 512000;         // 512*300 = 153600
  float* actN = small + 153600;        // 2000*300 = 600000

  float* out = (float*)d_out;
  float* score_link = out + 2000;  // 2000 x 512

  k_token<<<1024, 64, 0, stream>>>(fast_text, char_table, w3, b3, w4, b4, w5, b5,
                                   word_ids, char_ids, lstm_in);
  gemm_nt<<<dim3(16, 10), 256, 0, stream>>>(lstm_in, Wi_f, b_f, xpF, 1024, 600, 450);
  gemm_nt<<<dim3(16, 10), 256, 0, stream>>>(lstm_in, Wi_b, b_b, xpB, 1024, 600, 450);
  k_lstm<<<2, 640, 0, stream>>>(xpF, xpB, Wh_f, Wh_b, keys);
  k_renorm<<<2000, 64, 0, stream>>>(actor_matrix, actN);
  k_span<<<512, 320, 0, stream>>>(keys, lstm_in, alpha_W1, alpha_b1, alpha_W2,
                                  alpha_b2, alpha_w_out, feat_table, espans, enc);
  k_affine<<<128, 320, 0, stream>>>(enc, affine_W, affine_b, small);
  gemm_nt<<<dim3(32, 8), 256, 0, stream>>>(actN, small, nullptr, score_link,
                                           2000, 512, 300);
  k_lse<<<2000, 64, 0, stream>>>(score_link, out);
}